// Round 1
// baseline (572.334 us; speedup 1.0000x reference)
//
#include <hip/hip_runtime.h>

// LightDeepFilterNet:
//   spec : (B=16, 1, T=4000, F=481, 2) f32
//   coefs: (B=16, FS=5, T=4000, NF=96, 2) f32
//   out  : (B=16, 1, T=4000, F=481, 2) f32
// out[b,t,f<96]  = sum_i cmul(spec[b, t+i-4, f], coefs[b, i, t, f])  (spec zero-padded before t=0)
// out[b,t,f>=96] = spec[b,t,f>=96]
// Memory-bound: ~740 MB ideal traffic -> ~117 us roofline at 6.3 TB/s.

constexpr int B = 16;
constexpr int T = 4000;
constexpr int F = 481;
constexpr int NF = 96;
constexpr int FS = 5;
constexpr int PAD_BEFORE = FS - 1;  // lookahead = 0

__global__ __launch_bounds__(256) void ldfn_kernel(
    const float2* __restrict__ spec,
    const float2* __restrict__ coefs,
    float2* __restrict__ out)
{
    unsigned int idx = blockIdx.x * blockDim.x + threadIdx.x;
    constexpr unsigned int N = (unsigned int)B * T * F;
    if (idx >= N) return;

    unsigned int f  = idx % F;
    unsigned int bt = idx / F;

    if (f >= NF) {
        // tail copy
        out[idx] = spec[idx];
        return;
    }

    unsigned int t = bt % T;
    unsigned int b = bt / T;

    const float2* cb = coefs + ((size_t)b * FS * T * NF) + (size_t)t * NF + f;
    const float2* sb = spec  + ((size_t)b * T * F) + f;

    float2 acc = make_float2(0.f, 0.f);
#pragma unroll
    for (int i = 0; i < FS; ++i) {
        int ts = (int)t + i - PAD_BEFORE;
        if (ts >= 0) {
            float2 s = sb[(size_t)ts * F];
            float2 c = cb[(size_t)i * T * NF];
            acc.x = fmaf(s.x, c.x, fmaf(-s.y, c.y, acc.x));
            acc.y = fmaf(s.x, c.y, fmaf( s.y, c.x, acc.y));
        }
    }
    out[idx] = acc;
}

extern "C" void kernel_launch(void* const* d_in, const int* in_sizes, int n_in,
                              void* d_out, int out_size, void* d_ws, size_t ws_size,
                              hipStream_t stream)
{
    const float2* spec  = (const float2*)d_in[0];
    const float2* coefs = (const float2*)d_in[1];
    float2* out = (float2*)d_out;

    constexpr unsigned int N = (unsigned int)B * T * F;  // complex elements
    dim3 block(256);
    dim3 grid((N + 255) / 256);
    ldfn_kernel<<<grid, block, 0, stream>>>(spec, coefs, out);
}

// Round 2
// 560.419 us; speedup vs baseline: 1.0213x; 1.0213x over previous
//
#include <hip/hip_runtime.h>

// LightDeepFilterNet:
//   spec : (B=16, 1, T=4000, F=481, 2) f32
//   coefs: (B=16, FS=5, T=4000, NF=96, 2) f32
//   out  : (B=16, 1, T=4000, F=481, 2) f32
// out[b,t,f<96]  = sum_i cmul(spec[b, t+i-4, f], coefs[b, i, t, f])  (zero-pad t<0)
// out[b,t,f>=96] = spec[b,t,f>=96]
//
// R2: split grid into DF-band blocks and tail-copy blocks (no intra-wave
// divergence), multiple elements per thread for memory-level parallelism.
// Copy threads: 8 independent float2 loads in flight (was 1).

constexpr int B = 16;
constexpr int T = 4000;
constexpr int F = 481;
constexpr int NF = 96;
constexpr int FS = 5;
constexpr int PAD_BEFORE = FS - 1;  // lookahead = 0
constexpr int TAIL = F - NF;        // 385

constexpr int DF_N = B * T * NF;    // 6,144,000 complex
constexpr int CP_N = B * T * TAIL;  // 24,640,000 complex

constexpr int BLK = 256;
constexpr int DF_EPT = 4;                 // DF elements per thread
constexpr int CP_EPT = 8;                 // copy elements per thread
constexpr int DF_EPB = BLK * DF_EPT;      // 1024
constexpr int CP_EPB = BLK * CP_EPT;      // 2048
constexpr int DF_BLOCKS = (DF_N + DF_EPB - 1) / DF_EPB;  // 6000 (exact)
constexpr int CP_BLOCKS = (CP_N + CP_EPB - 1) / CP_EPB;  // 12032

__global__ __launch_bounds__(BLK) void ldfn_kernel(
    const float2* __restrict__ spec,
    const float2* __restrict__ coefs,
    float2* __restrict__ out)
{
    const int bid = blockIdx.x;
    const int tid = threadIdx.x;

    if (bid < DF_BLOCKS) {
        // ---- Deep-filter band: f in [0,96) ----
        const int base = bid * DF_EPB + tid;  // DF_N % DF_EPB == 0 -> no bounds check
#pragma unroll
        for (int j = 0; j < DF_EPT; ++j) {
            const int i = base + j * BLK;
            const int f = i % NF;
            const int r = i / NF;       // r = b*T + t
            const int t = r % T;
            const int b = r / T;

            const float2* cb = coefs + ((size_t)b * FS * T * NF) + (size_t)t * NF + f;
            const float2* sb = spec + (size_t)r * F + f;  // spec row for tap i is r + (tap-4)

            float2 acc = make_float2(0.f, 0.f);
#pragma unroll
            for (int tap = 0; tap < FS; ++tap) {
                const int dt = tap - PAD_BEFORE;  // -4..0
                if (t + dt >= 0) {
                    float2 s = sb[(ptrdiff_t)dt * F];
                    float2 c = cb[(size_t)tap * T * NF];
                    acc.x = fmaf(s.x, c.x, fmaf(-s.y, c.y, acc.x));
                    acc.y = fmaf(s.x, c.y, fmaf( s.y, c.x, acc.y));
                }
            }
            out[(size_t)r * F + f] = acc;
        }
    } else {
        // ---- Tail copy: f in [96,481) ----
        const int base = (bid - DF_BLOCKS) * CP_EPB + tid;
        float2 v[CP_EPT];
        int    id[CP_EPT];
#pragma unroll
        for (int j = 0; j < CP_EPT; ++j) {
            const int q = base + j * BLK;
            id[j] = -1;
            if (q < CP_N) {
                const int r  = q / TAIL;
                const int ff = q - r * TAIL;
                const int g  = r * F + NF + ff;
                id[j] = g;
                v[j] = spec[g];
            }
        }
#pragma unroll
        for (int j = 0; j < CP_EPT; ++j) {
            if (id[j] >= 0) out[id[j]] = v[j];
        }
    }
}

extern "C" void kernel_launch(void* const* d_in, const int* in_sizes, int n_in,
                              void* d_out, int out_size, void* d_ws, size_t ws_size,
                              hipStream_t stream)
{
    const float2* spec  = (const float2*)d_in[0];
    const float2* coefs = (const float2*)d_in[1];
    float2* out = (float2*)d_out;

    dim3 block(BLK);
    dim3 grid(DF_BLOCKS + CP_BLOCKS);
    ldfn_kernel<<<grid, block, 0, stream>>>(spec, coefs, out);
}